// Round 4
// baseline (258.150 us; speedup 1.0000x reference)
//
#include <hip/hip_runtime.h>

// CSR SpMV: y[r] = sum_{j in [ro[r], ro[r+1])} sx[j] * x[sel[j]]
// NNZ = 32M, ROWS = 1M (+1 offsets), COLS = 1M.
//
// R4 vs R3 (258us, FETCH 231MB == mandatory, HBM 15%, VALU 6%):
// bound on per-CU divergent gather-request cost (~5 cyc/request through the
// L1/TCP miss path; x = 4MB -> ~0% L1 hit, fills are pure overhead).
// Change: x-gathers now use raw buffer_load with sc0 (L1 bypass, served
// straight from per-XCD L2 where x is resident). Everything else unchanged.

constexpr int ITEMS     = 16;              // nnz per thread
constexpr int BLOCK     = 256;
constexpr int CHUNK_NNZ = BLOCK * ITEMS;   // 4096 nnz per block
constexpr int SRO_CAP   = 4098;            // LDS row-offset cache (16.4 KB)

typedef float f32x4 __attribute__((ext_vector_type(4)));
typedef int   i32x4 __attribute__((ext_vector_type(4)));
typedef int   v4i   __attribute__((ext_vector_type(4)));

// CK-style raw buffer load intrinsic; aux=1 -> sc0 (bypass CU L1 on gfx950)
__device__ float llvm_amdgcn_raw_buffer_load_fp32(v4i rsrc, int voffset,
                                                  int soffset, int aux)
    __asm("llvm.amdgcn.raw.buffer.load.f32");

union BufferRsrc {
    v4i v;
    struct {
        unsigned long long ptr;     // word0-1: base (stride bits zero)
        unsigned           range;   // word2: num_records (bytes)
        unsigned           config;  // word3: 0x00020000 raw dword access
    } s;
};

__global__ __launch_bounds__(256) void zero_out(float* __restrict__ y, int n) {
    int i = blockIdx.x * blockDim.x + threadIdx.x;
    if (i < n) y[i] = 0.0f;
}

// upper_bound over ro[1..num_rows], returns row r with ro[r] <= key < ro[r+1]
__device__ __forceinline__ int row_of(const int* __restrict__ ro,
                                      int num_rows, int key) {
    int left = 1, right = num_rows;
    while (left < right) {
        int mid = (left + right) >> 1;
        if (ro[mid] <= key) left = mid + 1; else right = mid;
    }
    return left - 1;
}

__global__ __launch_bounds__(BLOCK) void spmv_chunk(
    const float* __restrict__ sx,
    const float* __restrict__ x,
    const int*   __restrict__ sel,
    const int*   __restrict__ ro,   // length num_rows+1, ro[0]=0, ro[nr]=nnz
    float*       __restrict__ y,
    int nnz, int num_rows)
{
    __shared__ int sro[SRO_CAP];
    __shared__ int s_lo, s_hi;

    const int b  = blockIdx.x;
    const int B0 = b * CHUNK_NNZ;
    const int B1 = min(nnz, B0 + CHUNK_NNZ);

    if (threadIdx.x == 0)         s_lo = row_of(ro, num_rows, B0);
    if (threadIdx.x == BLOCK - 1) s_hi = row_of(ro, num_rows, B1 - 1);
    __syncthreads();

    const int lo = s_lo;
    const int n  = s_hi + 2 - lo;        // cache ro[lo .. hi+1], n entries
    const bool use_lds = (n <= SRO_CAP);
    if (use_lds) {
        for (int i = threadIdx.x; i < n; i += BLOCK) sro[i] = ro[lo + i];
    }
    __syncthreads();

    const int j0 = (b * BLOCK + threadIdx.x) * ITEMS;
    if (j0 >= nnz) return;               // after all barriers — safe
    const int j1 = min(nnz, j0 + ITEMS);

    // wave-uniform SRD for x (compiler hoists to SGPRs)
    BufferRsrc xr;
    xr.s.ptr    = (unsigned long long)x;
    xr.s.range  = 0xFFFFFFFFu;
    xr.s.config = 0x00020000u;

    float sum = 0.0f;

    if (use_lds && j1 - j0 == ITEMS) {
        // Phase 0: row start via LDS binary search
        int left = 1, right = n - 1;
        while (left < right) {
            int mid = (left + right) >> 1;
            if (sro[mid] <= j0) left = mid + 1; else right = mid;
        }
        int r_local  = left - 1;
        int row_end  = sro[r_local + 1];

        // Phase 1: stream sx/sel with nt loads; issue all 16 x-gathers (sc0).
        f32x4 s[ITEMS / 4];
        i32x4 c[ITEMS / 4];
        #pragma unroll
        for (int v = 0; v < ITEMS / 4; ++v) {
            s[v] = __builtin_nontemporal_load(
                       reinterpret_cast<const f32x4*>(sx + j0) + v);
            c[v] = __builtin_nontemporal_load(
                       reinterpret_cast<const i32x4*>(sel + j0) + v);
        }
        float p[ITEMS];
        #pragma unroll
        for (int v = 0; v < ITEMS / 4; ++v) {
            #pragma unroll
            for (int k = 0; k < 4; ++k) {
                float xv = llvm_amdgcn_raw_buffer_load_fp32(
                               xr.v, c[v][k] << 2, 0, /*aux=sc0*/ 1);
                p[v * 4 + k] = s[v][k] * xv;
            }
        }

        // Phase 2: row-walk accumulation, offsets from LDS, atomic per row.
        #pragma unroll
        for (int k = 0; k < ITEMS; ++k) {
            int jj = j0 + k;
            while (jj >= row_end) {              // handles empty rows
                if (sum != 0.0f) atomicAdd(&y[lo + r_local], sum);
                sum = 0.0f;
                ++r_local;
                row_end = sro[r_local + 1];
            }
            sum += p[k];
        }
        if (sum != 0.0f) atomicAdd(&y[lo + r_local], sum);
    } else {
        // Fallback (row-range exceeded LDS cap, or partial tail chunk).
        int r       = row_of(ro, num_rows, j0);
        int row_end = ro[r + 1];
        for (int j = j0; j < j1; ++j) {
            while (j >= row_end) {
                if (sum != 0.0f) atomicAdd(&y[r], sum);
                sum = 0.0f;
                ++r;
                row_end = ro[r + 1];
            }
            sum += sx[j] * x[sel[j]];
        }
        if (sum != 0.0f) atomicAdd(&y[r], sum);
    }
}

extern "C" void kernel_launch(void* const* d_in, const int* in_sizes, int n_in,
                              void* d_out, int out_size, void* d_ws, size_t ws_size,
                              hipStream_t stream) {
    const float* sx  = (const float*)d_in[0];
    const float* x   = (const float*)d_in[1];
    // d_in[2] is the zero "y" input — unused; we zero d_out ourselves.
    const int*   sel = (const int*)d_in[3];
    const int*   ro  = (const int*)d_in[4];
    float*       y   = (float*)d_out;

    const int nnz      = in_sizes[0];
    const int num_rows = in_sizes[4] - 1;   // == out_size

    {
        int threads = 256;
        int blocks  = (out_size + threads - 1) / threads;
        zero_out<<<blocks, threads, 0, stream>>>(y, out_size);
    }
    {
        int blocks = (nnz + CHUNK_NNZ - 1) / CHUNK_NNZ;
        spmv_chunk<<<blocks, BLOCK, 0, stream>>>(sx, x, sel, ro, y, nnz, num_rows);
    }
}